// Round 6
// baseline (185.490 us; speedup 1.0000x reference)
//
#include <hip/hip_runtime.h>

// NeuralODE: y' = tanh(y@W1+b1)@W2+b2, fixed-step Dopri5, 48 static iters.
// R6 (corrected R5): 256 blocks x 512 thr, 32 rows/block (two 16-row
// sub-tiles), each wave owns ONE 16-feature tile (8 waves = 8 tiles = 128
// features; R5 crashed because 8 waves x 2 tiles addressed nonexistent tiles
// 8..15 -> OOB). Transposed MFMA scheme (H^T = W1^T Y^T, F^T = W2^T T^T);
// C-layout: batch-row = lane&15, feature = quad*4+reg -> contiguous packed
// b64 stage writes. Both sub-tiles processed per barrier-phase: single tight
// barrier domain, 2x per-wave in-phase ILP vs R4.

typedef __attribute__((ext_vector_type(8))) short short8;  // 8 bf16 = 4 VGPRs
typedef __attribute__((ext_vector_type(4))) float f32x4;

#define SL 136  // LDS row stride in shorts: 272B rows, 16B-aligned

__device__ __forceinline__ short f2bf(float f) {
  union { float f; unsigned u; } v; v.f = f;
  return (short)((v.u + 0x8000u) >> 16);  // round-half-up
}

// pack two f32 -> two bf16 in one dword
__device__ __forceinline__ unsigned pack2bf(float lo, float hi) {
  union { float f; unsigned u; } a, b; a.f = lo; b.f = hi;
  return __builtin_amdgcn_perm(b.u + 0x8000u, a.u + 0x8000u, 0x07060302u);
}

__device__ __forceinline__ float fast_tanh(float x) {
  float e = __expf(2.0f * x);
  return 1.0f - __fdividef(2.0f, e + 1.0f);
}

__global__ __launch_bounds__(512, 2)
void node_kernel(const float* __restrict__ tptr, const float* __restrict__ x,
                 const float* __restrict__ W1, const float* __restrict__ b1,
                 const float* __restrict__ W2, const float* __restrict__ b2,
                 float* __restrict__ out) {
  const int tid  = threadIdx.x;
  const int lane = tid & 63;
  const int w    = tid >> 6;       // wave 0..7; owns feature tile w
  const int q    = lane >> 4;      // quad
  const int mL   = lane & 15;      // batch-row index within each 16-row sub-tile
  const int ft   = w * 16;         // feature tile base
  const int blockRow = blockIdx.x * 32;

  __shared__ short YbA[16 * SL], YbB[16 * SL];  // staged Y' (bf16), sub-tiles A/B
  __shared__ short TbA[16 * SL], TbB[16 * SL];  // staged tanh hidden
  __shared__ float sred[512];
  __shared__ float spart[4][128];
  __shared__ float srowY[128], srowH[128], srowF[128], srowY2[128], srowF2[128], sscale[128];

  // ---------- weight A-fragments (W^T) + biases into registers ----------
  // A-frag 16x16x32: lane holds A[m = lane&15][k = q*8+j]; A = W^T so
  // value = W[k = kt*32+q*8+j][feat = ft + mL]. Shared by both sub-tiles.
  short8 w1t[4], w2t[4];
  f32x4 b1v, b2v;
#pragma unroll
  for (int r = 0; r < 4; ++r) { b1v[r] = b1[ft + q * 4 + r]; b2v[r] = b2[ft + q * 4 + r]; }
#pragma unroll
  for (int kt = 0; kt < 4; ++kt) {
    short8 v1, v2;
#pragma unroll
    for (int j = 0; j < 8; ++j) {
      const int k = kt * 32 + q * 8 + j;
      v1[j] = f2bf(W1[k * 128 + ft + mL]);
      v2[j] = f2bf(W2[k * 128 + ft + mL]);
    }
    w1t[kt] = v1; w2t[kt] = v2;
  }

  // ---------- block-wide sum (512 threads) ----------
  auto block_sum = [&](float v) -> float {
    sred[tid] = v;
    __syncthreads();
    if (tid < 64) {
      float s = 0.f;
#pragma unroll
      for (int i = 0; i < 8; ++i) s += sred[tid + 64 * i];
#pragma unroll
      for (int o = 32; o > 0; o >>= 1) s += __shfl_down(s, o, 64);
      if (tid == 0) sred[0] = s;
    }
    __syncthreads();
    float r = sred[0];
    __syncthreads();
    return r;
  };

  // ---------- one MLP layer for a single row (fp32, split-K=4) ----------
  auto mlp_layer = [&](const float* vin, const float* Wg, const float* bg,
                       float* vout, bool dotanh) {
    const int col = tid & 127, part = tid >> 7;
    float s = 0.f;
    const float* wp = Wg + (part * 32) * 128 + col;
#pragma unroll 8
    for (int j = 0; j < 32; ++j) s += vin[part * 32 + j] * wp[j * 128];
    spart[part][col] = s;
    __syncthreads();
    if (tid < 128) {
      float a = bg[tid] + spart[0][tid] + spart[1][tid] + spart[2][tid] + spart[3][tid];
      vout[tid] = dotanh ? fast_tanh(a) : a;
    }
    __syncthreads();
  };

  // ---------- dt0: faithful port of initial_step_size (row 0, fp32) ----------
  if (tid < 128) srowY[tid] = x[tid];
  __syncthreads();
  mlp_layer(srowY, W1, b1, srowH, true);
  mlp_layer(srowH, W2, b2, srowF, false);
  float t0 = 0.f, t1 = 0.f;
  if (tid < 128) {
    float sc = 1.4e-8f + fabsf(srowY[tid]) * 1.4e-8f;
    sscale[tid] = sc;
    float a = srowY[tid] / sc; t0 = a * a;
    float bq = srowF[tid] / sc; t1 = bq * bq;
  }
  float d0 = sqrtf(block_sum(t0));
  float d1 = sqrtf(block_sum(t1));
  float h0 = (d0 < 1e-5f || d1 < 1e-5f) ? 1e-6f : 0.01f * d0 / d1;
  if (tid < 128) srowY2[tid] = srowY[tid] + h0 * srowF[tid];
  __syncthreads();
  mlp_layer(srowY2, W1, b1, srowH, true);
  mlp_layer(srowH, W2, b2, srowF2, false);
  float t2 = 0.f;
  if (tid < 128) { float a = (srowF2[tid] - srowF[tid]) / sscale[tid]; t2 = a * a; }
  float d2 = sqrtf(block_sum(t2)) / h0;
  float h1 = (d1 <= 1e-15f && d2 <= 1e-15f) ? fmaxf(1e-6f, h0 * 1e-3f)
                                            : powf(0.01f / (d1 + d2), 0.2f);
  const float dt0v = fminf(100.f * h0, h1);

  // ---------- load state: yr[0] = sub-tile A (rows 0..15), yr[1] = B (16..31) ----------
  f32x4 yr[2];
#pragma unroll
  for (int s = 0; s < 2; ++s)
    yr[s] = *(const f32x4*)&x[(blockRow + s * 16 + mL) * 128 + ft + q * 4];

  // hoisted LDS offsets (shorts)
  const int wrOff = mL * SL + ft + q * 4;  // stage write (b64, 4 features)
  const int rdOff = mL * SL + q * 8;       // B-frag b128 reads, +kt*32

  // ---------- one dual-sub-tile f-eval ----------
  auto evalF2 = [&](const f32x4* yin, f32x4* kout) {
    // stage both sub-tiles (packed b64 writes)
    *(uint2*)&YbA[wrOff] = uint2{pack2bf(yin[0][0], yin[0][1]), pack2bf(yin[0][2], yin[0][3])};
    *(uint2*)&YbB[wrOff] = uint2{pack2bf(yin[1][0], yin[1][1]), pack2bf(yin[1][2], yin[1][3])};
    __syncthreads();
    // layer 1 both sub-tiles: 8 reads up front, then 8 MFMAs (2 indep chains)
    short8 rA[4], rB[4];
#pragma unroll
    for (int kt = 0; kt < 4; ++kt) {
      rA[kt] = *(const short8*)&YbA[rdOff + kt * 32];
      rB[kt] = *(const short8*)&YbB[rdOff + kt * 32];
    }
    f32x4 acc0 = b1v, acc1 = b1v;
#pragma unroll
    for (int kt = 0; kt < 4; ++kt) {
      acc0 = __builtin_amdgcn_mfma_f32_16x16x32_bf16(w1t[kt], rA[kt], acc0, 0, 0, 0);
      acc1 = __builtin_amdgcn_mfma_f32_16x16x32_bf16(w1t[kt], rB[kt], acc1, 0, 0, 0);
    }
    // tanh + stage hidden (8 independent chains)
    *(uint2*)&TbA[wrOff] = uint2{pack2bf(fast_tanh(acc0[0]), fast_tanh(acc0[1])),
                                 pack2bf(fast_tanh(acc0[2]), fast_tanh(acc0[3]))};
    *(uint2*)&TbB[wrOff] = uint2{pack2bf(fast_tanh(acc1[0]), fast_tanh(acc1[1])),
                                 pack2bf(fast_tanh(acc1[2]), fast_tanh(acc1[3]))};
    __syncthreads();
    // layer 2 both sub-tiles
    short8 tA[4], tB[4];
#pragma unroll
    for (int kt = 0; kt < 4; ++kt) {
      tA[kt] = *(const short8*)&TbA[rdOff + kt * 32];
      tB[kt] = *(const short8*)&TbB[rdOff + kt * 32];
    }
    f32x4 accF0 = b2v, accF1 = b2v;
#pragma unroll
    for (int kt = 0; kt < 4; ++kt) {
      accF0 = __builtin_amdgcn_mfma_f32_16x16x32_bf16(w2t[kt], tA[kt], accF0, 0, 0, 0);
      accF1 = __builtin_amdgcn_mfma_f32_16x16x32_bf16(w2t[kt], tB[kt], accF1, 0, 0, 0);
    }
    kout[0] = accF0; kout[1] = accF1;
  };

  // ---------- main fixed-step Dopri5 loop ----------
  const float T = tptr[0] / 10.0f;  // t[0] / TIMESCALE
  float tt = 0.f;
  f32x4 k1[2], k2[2], k3[2], k4[2], k5[2], k6[2], yv[2];

#pragma unroll 1
  for (int it = 0; it < 48; ++it) {
    float dt = fminf(fmaxf(T - tt, 0.f), dt0v);
    if (dt > 0.f) {  // uniform across all threads and blocks
      evalF2(yr, k1);
#pragma unroll
      for (int s = 0; s < 2; ++s) yv[s] = yr[s] + dt * (0.2f * k1[s]);
      evalF2(yv, k2);
#pragma unroll
      for (int s = 0; s < 2; ++s) yv[s] = yr[s] + dt * (0.075f * k1[s] + 0.225f * k2[s]);
      evalF2(yv, k3);
#pragma unroll
      for (int s = 0; s < 2; ++s)
        yv[s] = yr[s] + dt * (0.9777777777777777f * k1[s] - 3.7333333333333334f * k2[s]
                            + 3.5555555555555554f * k3[s]);
      evalF2(yv, k4);
#pragma unroll
      for (int s = 0; s < 2; ++s)
        yv[s] = yr[s] + dt * (2.9525986892242035f * k1[s] - 11.595793324188385f * k2[s]
                            + 9.822892851699436f * k3[s] - 0.2908093278463649f * k4[s]);
      evalF2(yv, k5);
#pragma unroll
      for (int s = 0; s < 2; ++s)
        yv[s] = yr[s] + dt * (2.8462752525252526f * k1[s] - 10.757575757575758f * k2[s]
                            + 8.906422717743473f * k3[s] + 0.2784090909090909f * k4[s]
                            - 0.27351165254237287f * k5[s]);
      evalF2(yv, k6);
#pragma unroll
      for (int s = 0; s < 2; ++s)
        yr[s] = yr[s] + dt * (0.0911458333333333f * k1[s] + 0.449236298292902f * k3[s]
                            + 0.6510416666666666f * k4[s] - 0.32237617924528303f * k5[s]
                            + 0.13095238095238096f * k6[s]);
    }
    tt += dt;
  }

  // ---------- epilogue: out = stack([x, yT]) ----------
  {
    const float4* x4 = (const float4*)(x + blockRow * 128);
    float4* o4 = (float4*)(out + blockRow * 128);
#pragma unroll
    for (int i = 0; i < 2; ++i) o4[tid + 512 * i] = x4[tid + 512 * i];
    float* oy = out + 8192 * 128;
#pragma unroll
    for (int s = 0; s < 2; ++s)
      *(f32x4*)&oy[(blockRow + s * 16 + mL) * 128 + ft + q * 4] = yr[s];
  }
}

extern "C" void kernel_launch(void* const* d_in, const int* in_sizes, int n_in,
                              void* d_out, int out_size, void* d_ws, size_t ws_size,
                              hipStream_t stream) {
  const float* t  = (const float*)d_in[0];
  const float* x  = (const float*)d_in[1];
  const float* W1 = (const float*)d_in[2];
  const float* b1 = (const float*)d_in[3];
  const float* W2 = (const float*)d_in[4];
  const float* b2 = (const float*)d_in[5];
  float* out = (float*)d_out;
  node_kernel<<<dim3(256), dim3(512), 0, stream>>>(t, x, W1, b1, W2, b2, out);
}

// Round 7
// 169.891 us; speedup vs baseline: 1.0918x; 1.0918x over previous
//
#include <hip/hip_runtime.h>

// NeuralODE: y' = tanh(y@W1+b1)@W2+b2, fixed-step Dopri5, 48 static iters.
// R7 = R4 (best, 126us) + XOR-swizzled LDS staging (SL=128, no pad):
//   16B chunk c of row m stored at c ^ (m&7)  -> B-frag ds_read_b128 spreads
//   across all 8 bank-groups uniformly (was: (mL+q)%8 stacking with SL=136,
//   SQ_LDS_BANK_CONFLICT=8.8e6). Writes use the equivalent 8B-granular key
//   2*(m&7). Pure address-map change; all offsets hoisted outside the loop.
// Config: 512 blocks x 256 thr (4 waves, 2 blocks/CU), 16 rows/block, each
// wave owns two 16-feature tiles. Transposed MFMA scheme: H^T = W1^T Y^T,
// F^T = W2^T T^T; C-layout: batch-row = lane&15, feature = quad*4+reg ->
// contiguous packed b64 stage writes. Weights as W^T A-frags in registers.

typedef __attribute__((ext_vector_type(8))) short short8;  // 8 bf16 = 4 VGPRs
typedef __attribute__((ext_vector_type(4))) float f32x4;

__device__ __forceinline__ short f2bf(float f) {
  union { float f; unsigned u; } v; v.f = f;
  return (short)((v.u + 0x8000u) >> 16);  // round-half-up
}

// pack two f32 -> two bf16 in one dword
__device__ __forceinline__ unsigned pack2bf(float lo, float hi) {
  union { float f; unsigned u; } a, b; a.f = lo; b.f = hi;
  return __builtin_amdgcn_perm(b.u + 0x8000u, a.u + 0x8000u, 0x07060302u);
}

__device__ __forceinline__ float fast_tanh(float x) {
  float e = __expf(2.0f * x);
  return 1.0f - __fdividef(2.0f, e + 1.0f);
}

__global__ __launch_bounds__(256, 2)
void node_kernel(const float* __restrict__ tptr, const float* __restrict__ x,
                 const float* __restrict__ W1, const float* __restrict__ b1,
                 const float* __restrict__ W2, const float* __restrict__ b2,
                 float* __restrict__ out) {
  const int tid  = threadIdx.x;
  const int lane = tid & 63;
  const int w    = tid >> 6;       // wave 0..3; owns feature tiles 2w, 2w+1
  const int q    = lane >> 4;      // quad
  const int mL   = lane & 15;      // batch-row index within 16-row block
  const int blockRow = blockIdx.x * 16;

  __shared__ short Yb[16 * 128];   // staged Y' (bf16), XOR-swizzled rows
  __shared__ short Tb[16 * 128];   // staged tanh hidden (bf16), swizzled
  __shared__ float sred[256];
  __shared__ float spart[2][128];
  __shared__ float srowY[128], srowH[128], srowF[128], srowY2[128], srowF2[128], sscale[128];

  // ---------- weight A-fragments (W^T) + biases into registers ----------
  // A-frag 16x16x32: lane holds A[m = lane&15][k = q*8+j]; A = W^T so
  // value = W[k = kt*32+q*8+j][feat = tile*16 + mL].
  short8 w1t[2][4], w2t[2][4];
  f32x4 b1v[2], b2v[2];
#pragma unroll
  for (int s = 0; s < 2; ++s) {
    const int ft = (2 * w + s) * 16;
#pragma unroll
    for (int r = 0; r < 4; ++r) { b1v[s][r] = b1[ft + q * 4 + r]; b2v[s][r] = b2[ft + q * 4 + r]; }
#pragma unroll
    for (int kt = 0; kt < 4; ++kt) {
      short8 v1, v2;
#pragma unroll
      for (int j = 0; j < 8; ++j) {
        const int k = kt * 32 + q * 8 + j;
        v1[j] = f2bf(W1[k * 128 + ft + mL]);
        v2[j] = f2bf(W2[k * 128 + ft + mL]);
      }
      w1t[s][kt] = v1; w2t[s][kt] = v2;
    }
  }

  // ---------- block-wide sum ----------
  auto block_sum = [&](float v) -> float {
    sred[tid] = v;
    __syncthreads();
    if (tid < 64) {
      float s = sred[tid] + sred[tid + 64] + sred[tid + 128] + sred[tid + 192];
#pragma unroll
      for (int o = 32; o > 0; o >>= 1) s += __shfl_down(s, o, 64);
      if (tid == 0) sred[0] = s;
    }
    __syncthreads();
    float r = sred[0];
    __syncthreads();
    return r;
  };

  // ---------- one MLP layer for a single row (fp32, split-K=2) ----------
  auto mlp_layer = [&](const float* vin, const float* Wg, const float* bg,
                       float* vout, bool dotanh) {
    const int col = tid & 127, part = tid >> 7;
    float s = 0.f;
    const float* wp = Wg + (part * 64) * 128 + col;
#pragma unroll 8
    for (int j = 0; j < 64; ++j) s += vin[part * 64 + j] * wp[j * 128];
    spart[part][col] = s;
    __syncthreads();
    if (tid < 128) {
      float a = bg[tid] + spart[0][tid] + spart[1][tid];
      vout[tid] = dotanh ? fast_tanh(a) : a;
    }
    __syncthreads();
  };

  // ---------- dt0: faithful port of initial_step_size (row 0, fp32) ----------
  if (tid < 128) srowY[tid] = x[tid];
  __syncthreads();
  mlp_layer(srowY, W1, b1, srowH, true);
  mlp_layer(srowH, W2, b2, srowF, false);
  float t0 = 0.f, t1 = 0.f;
  if (tid < 128) {
    float sc = 1.4e-8f + fabsf(srowY[tid]) * 1.4e-8f;
    sscale[tid] = sc;
    float a = srowY[tid] / sc; t0 = a * a;
    float bq = srowF[tid] / sc; t1 = bq * bq;
  }
  float d0 = sqrtf(block_sum(t0));
  float d1 = sqrtf(block_sum(t1));
  float h0 = (d0 < 1e-5f || d1 < 1e-5f) ? 1e-6f : 0.01f * d0 / d1;
  if (tid < 128) srowY2[tid] = srowY[tid] + h0 * srowF[tid];
  __syncthreads();
  mlp_layer(srowY2, W1, b1, srowH, true);
  mlp_layer(srowH, W2, b2, srowF2, false);
  float t2 = 0.f;
  if (tid < 128) { float a = (srowF2[tid] - srowF[tid]) / sscale[tid]; t2 = a * a; }
  float d2 = sqrtf(block_sum(t2)) / h0;
  float h1 = (d1 <= 1e-15f && d2 <= 1e-15f) ? fmaxf(1e-6f, h0 * 1e-3f)
                                            : powf(0.01f / (d1 + d2), 0.2f);
  const float dt0v = fminf(100.f * h0, h1);

  // ---------- load state Y (transposed C-layout: m=mL, feat contiguous) ----------
  f32x4 yr[2];
#pragma unroll
  for (int s = 0; s < 2; ++s)
    yr[s] = *(const f32x4*)&x[(blockRow + mL) * 128 + (2 * w + s) * 16 + q * 4];

  // ---------- swizzled LDS offsets (shorts), all loop-invariant ----------
  // write: 8B chunk c8 (feats 4*c8..4*c8+3) of row m stored at 4*(c8 ^ (2*(m&7)))
  // read: 16B chunk c16 (feats 8*c16..) of row m stored at 8*(c16 ^ (m&7))
  const int key  = mL & 7;
  const int base = mL * 128;
  const int wrOff0 = base + 4 * ((8 * w + q)     ^ (2 * key));  // tile 2w
  const int wrOff1 = base + 4 * ((8 * w + 4 + q) ^ (2 * key));  // tile 2w+1
  int rdk[4];
#pragma unroll
  for (int kt = 0; kt < 4; ++kt) rdk[kt] = base + 8 * ((q + 4 * kt) ^ key);

  // ---------- one f-eval ----------
  auto evalF = [&](const f32x4* yin, f32x4* kout) {
    // stage Y' (packed b64 per tile, swizzled)
    *(uint2*)&Yb[wrOff0] = uint2{pack2bf(yin[0][0], yin[0][1]), pack2bf(yin[0][2], yin[0][3])};
    *(uint2*)&Yb[wrOff1] = uint2{pack2bf(yin[1][0], yin[1][1]), pack2bf(yin[1][2], yin[1][3])};
    __syncthreads();
    // layer 1: H^T = W1^T · Y^T  (one B read feeds both tiles' MFMAs)
    f32x4 acc0 = b1v[0], acc1 = b1v[1];
    short8 rb0 = *(const short8*)&Yb[rdk[0]];
    short8 rb1 = *(const short8*)&Yb[rdk[1]];
    short8 rb2 = *(const short8*)&Yb[rdk[2]];
    short8 rb3 = *(const short8*)&Yb[rdk[3]];
    acc0 = __builtin_amdgcn_mfma_f32_16x16x32_bf16(w1t[0][0], rb0, acc0, 0, 0, 0);
    acc1 = __builtin_amdgcn_mfma_f32_16x16x32_bf16(w1t[1][0], rb0, acc1, 0, 0, 0);
    acc0 = __builtin_amdgcn_mfma_f32_16x16x32_bf16(w1t[0][1], rb1, acc0, 0, 0, 0);
    acc1 = __builtin_amdgcn_mfma_f32_16x16x32_bf16(w1t[1][1], rb1, acc1, 0, 0, 0);
    acc0 = __builtin_amdgcn_mfma_f32_16x16x32_bf16(w1t[0][2], rb2, acc0, 0, 0, 0);
    acc1 = __builtin_amdgcn_mfma_f32_16x16x32_bf16(w1t[1][2], rb2, acc1, 0, 0, 0);
    acc0 = __builtin_amdgcn_mfma_f32_16x16x32_bf16(w1t[0][3], rb3, acc0, 0, 0, 0);
    acc1 = __builtin_amdgcn_mfma_f32_16x16x32_bf16(w1t[1][3], rb3, acc1, 0, 0, 0);
    // tanh + stage hidden (swizzled)
    *(uint2*)&Tb[wrOff0] = uint2{pack2bf(fast_tanh(acc0[0]), fast_tanh(acc0[1])),
                                 pack2bf(fast_tanh(acc0[2]), fast_tanh(acc0[3]))};
    *(uint2*)&Tb[wrOff1] = uint2{pack2bf(fast_tanh(acc1[0]), fast_tanh(acc1[1])),
                                 pack2bf(fast_tanh(acc1[2]), fast_tanh(acc1[3]))};
    __syncthreads();
    // layer 2: F^T = W2^T · T^T
    f32x4 accF0 = b2v[0], accF1 = b2v[1];
    short8 tb0 = *(const short8*)&Tb[rdk[0]];
    short8 tb1 = *(const short8*)&Tb[rdk[1]];
    short8 tb2 = *(const short8*)&Tb[rdk[2]];
    short8 tb3 = *(const short8*)&Tb[rdk[3]];
    accF0 = __builtin_amdgcn_mfma_f32_16x16x32_bf16(w2t[0][0], tb0, accF0, 0, 0, 0);
    accF1 = __builtin_amdgcn_mfma_f32_16x16x32_bf16(w2t[1][0], tb0, accF1, 0, 0, 0);
    accF0 = __builtin_amdgcn_mfma_f32_16x16x32_bf16(w2t[0][1], tb1, accF0, 0, 0, 0);
    accF1 = __builtin_amdgcn_mfma_f32_16x16x32_bf16(w2t[1][1], tb1, accF1, 0, 0, 0);
    accF0 = __builtin_amdgcn_mfma_f32_16x16x32_bf16(w2t[0][2], tb2, accF0, 0, 0, 0);
    accF1 = __builtin_amdgcn_mfma_f32_16x16x32_bf16(w2t[1][2], tb2, accF1, 0, 0, 0);
    accF0 = __builtin_amdgcn_mfma_f32_16x16x32_bf16(w2t[0][3], tb3, accF0, 0, 0, 0);
    accF1 = __builtin_amdgcn_mfma_f32_16x16x32_bf16(w2t[1][3], tb3, accF1, 0, 0, 0);
    kout[0] = accF0; kout[1] = accF1;
  };

  // ---------- main fixed-step Dopri5 loop ----------
  const float T = tptr[0] / 10.0f;  // t[0] / TIMESCALE
  float tt = 0.f;
  f32x4 k1[2], k2[2], k3[2], k4[2], k5[2], k6[2], yv[2];

#pragma unroll 1
  for (int it = 0; it < 48; ++it) {
    float dt = fminf(fmaxf(T - tt, 0.f), dt0v);
    if (dt > 0.f) {  // uniform across all threads and blocks
      evalF(yr, k1);
#pragma unroll
      for (int s = 0; s < 2; ++s) yv[s] = yr[s] + dt * (0.2f * k1[s]);
      evalF(yv, k2);
#pragma unroll
      for (int s = 0; s < 2; ++s) yv[s] = yr[s] + dt * (0.075f * k1[s] + 0.225f * k2[s]);
      evalF(yv, k3);
#pragma unroll
      for (int s = 0; s < 2; ++s)
        yv[s] = yr[s] + dt * (0.9777777777777777f * k1[s] - 3.7333333333333334f * k2[s]
                            + 3.5555555555555554f * k3[s]);
      evalF(yv, k4);
#pragma unroll
      for (int s = 0; s < 2; ++s)
        yv[s] = yr[s] + dt * (2.9525986892242035f * k1[s] - 11.595793324188385f * k2[s]
                            + 9.822892851699436f * k3[s] - 0.2908093278463649f * k4[s]);
      evalF(yv, k5);
#pragma unroll
      for (int s = 0; s < 2; ++s)
        yv[s] = yr[s] + dt * (2.8462752525252526f * k1[s] - 10.757575757575758f * k2[s]
                            + 8.906422717743473f * k3[s] + 0.2784090909090909f * k4[s]
                            - 0.27351165254237287f * k5[s]);
      evalF(yv, k6);
#pragma unroll
      for (int s = 0; s < 2; ++s)
        yr[s] = yr[s] + dt * (0.0911458333333333f * k1[s] + 0.449236298292902f * k3[s]
                            + 0.6510416666666666f * k4[s] - 0.32237617924528303f * k5[s]
                            + 0.13095238095238096f * k6[s]);
    }
    tt += dt;
  }

  // ---------- epilogue: out = stack([x, yT]) ----------
  {
    const float4* x4 = (const float4*)(x + blockRow * 128);
    float4* o4 = (float4*)(out + blockRow * 128);
#pragma unroll
    for (int i = 0; i < 2; ++i) o4[tid + 256 * i] = x4[tid + 256 * i];
    float* oy = out + 8192 * 128;
#pragma unroll
    for (int s = 0; s < 2; ++s)
      *(f32x4*)&oy[(blockRow + mL) * 128 + (2 * w + s) * 16 + q * 4] = yr[s];
  }
}

extern "C" void kernel_launch(void* const* d_in, const int* in_sizes, int n_in,
                              void* d_out, int out_size, void* d_ws, size_t ws_size,
                              hipStream_t stream) {
  const float* t  = (const float*)d_in[0];
  const float* x  = (const float*)d_in[1];
  const float* W1 = (const float*)d_in[2];
  const float* b1 = (const float*)d_in[3];
  const float* W2 = (const float*)d_in[4];
  const float* b2 = (const float*)d_in[5];
  float* out = (float*)d_out;
  node_kernel<<<dim3(512), dim3(256), 0, stream>>>(t, x, W1, b1, W2, b2, out);
}